// Round 3
// baseline (1294.709 us; speedup 1.0000x reference)
//
#include <hip/hip_runtime.h>
#include <math.h>

#define NB 65536
#define DIM 256

// One cyclic-MoE layer, pure VALU fp32 (no MFMA) — correctness-first diagnostic.
// Out[b,:] = act( sum_e C[b,e] * (X[b,:] @ W_e + bias_e) )
// Block: 256 threads; tile = 16 rows x 256 cols (one col per thread, 16 rows each).
template<bool RELU>
__global__ __launch_bounds__(256) void moe_layer_valu(
    const float* __restrict__ Xin,
    const float* __restrict__ phi,
    const float* __restrict__ W,     // [4,256,256] = [e][k][n]
    const float* __restrict__ bias,  // [4,256]
    float* __restrict__ Out)
{
  __shared__ float sX[16][260];   // 16 rows x 256 cols (+4 pad), ~16.6 KB
  __shared__ float sC[16][4];     // per-row expert coefficients

  const int tid  = threadIdx.x;
  const int row0 = blockIdx.x * 16;

  // --- stage X tile: 1024 float4 over 256 threads x 4 iters ---
  #pragma unroll
  for (int it = 0; it < 4; ++it) {
    const int f4 = it * 256 + tid;       // 0..1023
    const int r  = f4 >> 6;              // 64 float4 per row
    const int c4 = (f4 & 63) * 4;
    *(float4*)&sX[r][c4] = *(const float4*)(Xin + (size_t)(row0 + r) * DIM + c4);
  }

  // --- per-row mixing coefficients (reference _phase_mix, verbatim) ---
  if (tid < 16) {
    const float w  = phi[row0 + tid] * (float)(2.0 / M_PI);  // [0,4]
    const int   wi = (int)w;                                 // trunc toward zero
    const float w2 = w * w, w3 = w2 * w;
    const float cf[4] = {
      -0.5f * w + w2 - 0.5f * w3,
      -2.5f * w2 + 1.5f * w3,
       0.5f * w + 2.0f * w2 - 1.5f * w3,
      -0.5f * w2 + 0.5f * w3 };
    #pragma unroll
    for (int e = 0; e < 4; ++e) sC[tid][e] = cf[(e + 1 - wi) & 3];  // (wi+i-1)%4==e
  }
  __syncthreads();

  const int col = tid;  // output column this thread owns

  float acc[16][4];
  #pragma unroll
  for (int r = 0; r < 16; ++r)
    #pragma unroll
    for (int e = 0; e < 4; ++e) acc[r][e] = 0.f;

  // --- K loop: 4 coalesced W loads per k (one per expert), 64 FMAs ---
  #pragma unroll 4
  for (int k = 0; k < DIM; ++k) {
    const float we0 = W[(size_t)(0 * DIM + k) * DIM + col];
    const float we1 = W[(size_t)(1 * DIM + k) * DIM + col];
    const float we2 = W[(size_t)(2 * DIM + k) * DIM + col];
    const float we3 = W[(size_t)(3 * DIM + k) * DIM + col];
    #pragma unroll
    for (int r = 0; r < 16; ++r) {
      const float xv = sX[r][k];   // broadcast (same addr across lanes)
      acc[r][0] = fmaf(xv, we0, acc[r][0]);
      acc[r][1] = fmaf(xv, we1, acc[r][1]);
      acc[r][2] = fmaf(xv, we2, acc[r][2]);
      acc[r][3] = fmaf(xv, we3, acc[r][3]);
    }
  }

  // --- epilogue: per-row mix + bias + activation, coalesced store ---
  const float b0 = bias[0 * DIM + col];
  const float b1 = bias[1 * DIM + col];
  const float b2 = bias[2 * DIM + col];
  const float b3 = bias[3 * DIM + col];
  #pragma unroll
  for (int r = 0; r < 16; ++r) {
    float v = sC[r][0] * (acc[r][0] + b0)
            + sC[r][1] * (acc[r][1] + b1)
            + sC[r][2] * (acc[r][2] + b2)
            + sC[r][3] * (acc[r][3] + b3);
    if (RELU) v = fmaxf(v, 0.f);
    Out[(size_t)(row0 + r) * DIM + col] = v;
  }
}

extern "C" void kernel_launch(void* const* d_in, const int* in_sizes, int n_in,
                              void* d_out, int out_size, void* d_ws, size_t ws_size,
                              hipStream_t stream) {
  const float* X   = (const float*)d_in[0];
  const float* phi = (const float*)d_in[1];
  const float* W1  = (const float*)d_in[2];
  const float* b1  = (const float*)d_in[3];
  const float* W2  = (const float*)d_in[4];
  const float* b2  = (const float*)d_in[5];
  const float* W3  = (const float*)d_in[6];
  const float* b3  = (const float*)d_in[7];

  // Buffer plan (defensive about ws_size):
  //   H1 = d_out (dead before layer-3 writes).
  //   H2 = d_ws if it fits 64 MB, else reuse the X input buffer (X is dead
  //        after layer 1; harness restores d_in before every timed launch).
  // Branch depends only on ws_size (constant) -> identical work every call.
  const size_t needed = (size_t)NB * DIM * sizeof(float);
  float* H1  = (float*)d_out;
  float* H2  = (ws_size >= needed) ? (float*)d_ws : (float*)d_in[0];
  float* out = (float*)d_out;

  dim3 grid(NB / 16);
  dim3 block(256);

  moe_layer_valu<true ><<<grid, block, 0, stream>>>(X,  phi, W1, b1, H1);
  moe_layer_valu<true ><<<grid, block, 0, stream>>>(H1, phi, W2, b2, H2);
  moe_layer_valu<false><<<grid, block, 0, stream>>>(H2, phi, W3, b3, out);
}

// Round 5
// 1264.997 us; speedup vs baseline: 1.0235x; 1.0235x over previous
//
#include <hip/hip_runtime.h>
#include <math.h>

#define NB 65536
#define DIM 256

typedef __attribute__((ext_vector_type(8))) short bf16x8;
typedef __attribute__((ext_vector_type(4))) float f32x4;

__device__ __forceinline__ unsigned short f2bf(float f) {
  // round-to-nearest-even float -> bf16 bits
  unsigned int u = __float_as_uint(f);
  return (unsigned short)((u + 0x7fffu + ((u >> 16) & 1u)) >> 16);
}
__device__ __forceinline__ float bf2f(unsigned short h) {
  union { unsigned int u; float f; } v; v.u = ((unsigned int)h) << 16; return v.f;
}

// One cyclic-MoE layer, split-bf16 (hi+lo) GEMM for ~fp32 accuracy, with
// RUNTIME-PROBED MFMA C/D layout (immune to row/col-map convention errors).
// Out[b,:] = act( sum_e C[b,e] * (X[b,:] @ W_e + bias_e) ), fp32 in / fp32 out.
// Block: 256 threads (4 waves). Tile: 64 rows x 32 cols. K = 256 (full).
template<bool RELU>
__global__ __launch_bounds__(256) void moe_layer(
    const float* __restrict__ Xin,
    const float* __restrict__ phi,
    const float* __restrict__ W,     // [4,256,256] row-major [e][k][n]
    const float* __restrict__ bias,  // [4,256]
    float* __restrict__ Out)
{
  __shared__ unsigned short sBh[32][264];  // W_e tile hi, transposed [n_local][k]
  __shared__ unsigned short sBl[32][264];  // W_e tile lo
  __shared__ float sC[64][4];              // per-row expert coefficients
  __shared__ float sBias[4][32];

  const int tid  = threadIdx.x;
  const int row0 = blockIdx.x * 64;
  const int n0   = blockIdx.y * 32;
  const int wave = tid >> 6;
  const int lane = tid & 63;
  const int quad = lane >> 4;
  const int l15  = lane & 15;

  // --- LAYOUT PROBE: measure the true (lane,reg)->(row,col) C/D mapping ---
  // pm = (A=lane_id) x (B=ones):  D[m][n] = 32*m  -> pm[r] = 32*row(lane,r)
  // pn = (A=ones) x (B=lane_id):  D[m][n] = 32*n  -> pn[r] = 32*col(lane,r)
  // Values 0..15 exact in bf16; sums exact in fp32. This measures the
  // composite of the real A/B operand maps and the real C/D map — exactly
  // the relation the combine/store indexing needs.
  int rowId[4], colId[4];
  {
    bf16x8 vone, vlan;
    const unsigned short ob = f2bf(1.0f);
    const unsigned short lb = f2bf((float)l15);
    #pragma unroll
    for (int j = 0; j < 8; ++j) { vone[j] = (short)ob; vlan[j] = (short)lb; }
    const f32x4 z4 = {0.f, 0.f, 0.f, 0.f};
    const f32x4 pm = __builtin_amdgcn_mfma_f32_16x16x32_bf16(vlan, vone, z4, 0, 0, 0);
    const f32x4 pn = __builtin_amdgcn_mfma_f32_16x16x32_bf16(vone, vlan, z4, 0, 0, 0);
    #pragma unroll
    for (int r = 0; r < 4; ++r) {
      rowId[r] = ((int)(pm[r] * 0.03125f + 0.5f)) & 15;
      colId[r] = ((int)(pn[r] * 0.03125f + 0.5f)) & 15;
    }
  }

  // --- per-row mixing coefficients (reference _phase_mix) ---
  if (tid < 64) {
    const float w  = phi[row0 + tid] * (float)(2.0 / M_PI);  // [0,4]
    const int   wi = (int)w;                                 // trunc toward zero
    const float w2 = w * w, w3 = w2 * w;
    const float cf[4] = {
      -0.5f * w + w2 - 0.5f * w3,
      -2.5f * w2 + 1.5f * w3,
       0.5f * w + 2.0f * w2 - 1.5f * w3,
      -0.5f * w2 + 0.5f * w3 };
    #pragma unroll
    for (int e = 0; e < 4; ++e) sC[tid][e] = cf[(e + 1 - wi) & 3];  // expert e <- coeff i, (wi+i-1)%4==e
  }
  if (tid < 128) {
    int e = tid >> 5, n = tid & 31;
    sBias[e][n] = bias[e * DIM + n0 + n];
  }

  // --- A fragments (hi/lo), hoisted across experts ---
  // Row wave*16+l15 loaded at lane l15; probe pm tells us where it lands in D.
  bf16x8 ah[8], al[8];
  const float* xrow = Xin + (size_t)(row0 + wave * 16 + l15) * DIM;
  #pragma unroll
  for (int kb = 0; kb < 8; ++kb) {
    const float4 a = *(const float4*)(xrow + kb * 32 + quad * 8);
    const float4 b = *(const float4*)(xrow + kb * 32 + quad * 8 + 4);
    const float xs[8] = {a.x, a.y, a.z, a.w, b.x, b.y, b.z, b.w};
    bf16x8 h, l;
    #pragma unroll
    for (int j = 0; j < 8; ++j) {
      const unsigned short hb = f2bf(xs[j]);
      h[j] = (short)hb;
      l[j] = (short)f2bf(xs[j] - bf2f(hb));
    }
    ah[kb] = h; al[kb] = l;
  }

  float fin[2][4];
  #pragma unroll
  for (int t = 0; t < 2; ++t)
    #pragma unroll
    for (int r = 0; r < 4; ++r) fin[t][r] = 0.f;

  for (int e = 0; e < 4; ++e) {
    __syncthreads();  // prev sBh/sBl reads done; also covers sC/sBias at e=0

    // --- stage W_e[:, n0:n0+32] hi/lo transposed into LDS ---
    const float* We = W + (size_t)e * DIM * DIM + n0;
    #pragma unroll
    for (int it = 0; it < 8; ++it) {
      const int f4 = it * 256 + tid;       // 2048 float4 = 256 k-rows x 8 float4
      const int k  = f4 >> 3;
      const int c  = (f4 & 7) * 4;
      const float4 v = *(const float4*)(We + (size_t)k * DIM + c);
      const float vs[4] = {v.x, v.y, v.z, v.w};
      #pragma unroll
      for (int j = 0; j < 4; ++j) {
        const unsigned short hb = f2bf(vs[j]);
        sBh[c + j][k] = hb;
        sBl[c + j][k] = f2bf(vs[j] - bf2f(hb));
      }
    }
    __syncthreads();

    // --- split-bf16 MFMA over K=256: A*W ~= al*bh + ah*bl + ah*bh ---
    f32x4 acc[2];
    acc[0] = (f32x4){0.f, 0.f, 0.f, 0.f};
    acc[1] = (f32x4){0.f, 0.f, 0.f, 0.f};
    #pragma unroll
    for (int kb = 0; kb < 8; ++kb) {
      #pragma unroll
      for (int t = 0; t < 2; ++t) {
        const bf16x8 bh = *(const bf16x8*)&sBh[t * 16 + l15][kb * 32 + quad * 8];
        const bf16x8 bl = *(const bf16x8*)&sBl[t * 16 + l15][kb * 32 + quad * 8];
        acc[t] = __builtin_amdgcn_mfma_f32_16x16x32_bf16(al[kb], bh, acc[t], 0, 0, 0);
        acc[t] = __builtin_amdgcn_mfma_f32_16x16x32_bf16(ah[kb], bl, acc[t], 0, 0, 0);
        acc[t] = __builtin_amdgcn_mfma_f32_16x16x32_bf16(ah[kb], bh, acc[t], 0, 0, 0);
      }
    }

    // --- combine: fin += C[row,e] * acc_e, row from the probe ---
    #pragma unroll
    for (int r = 0; r < 4; ++r) {
      const float ce = sC[wave * 16 + rowId[r]][e];
      fin[0][r] += ce * acc[0][r];
      fin[1][r] += ce * acc[1][r];
    }
  }

  // --- epilogue: probe-driven row/col indexing ---
  #pragma unroll
  for (int r = 0; r < 4; ++r) {
    const int row_l = wave * 16 + rowId[r];
    #pragma unroll
    for (int t = 0; t < 2; ++t) {
      const int n_l = t * 16 + colId[r];
      float v = fin[t][r];
      #pragma unroll
      for (int e = 0; e < 4; ++e) v += sC[row_l][e] * sBias[e][n_l];
      if (RELU) v = fmaxf(v, 0.f);
      Out[(size_t)(row0 + row_l) * DIM + n0 + n_l] = v;
    }
  }
}

extern "C" void kernel_launch(void* const* d_in, const int* in_sizes, int n_in,
                              void* d_out, int out_size, void* d_ws, size_t ws_size,
                              hipStream_t stream) {
  const float* X   = (const float*)d_in[0];
  const float* phi = (const float*)d_in[1];
  const float* W1  = (const float*)d_in[2];
  const float* b1  = (const float*)d_in[3];
  const float* W2  = (const float*)d_in[4];
  const float* b2  = (const float*)d_in[5];
  const float* W3  = (const float*)d_in[6];
  const float* b3  = (const float*)d_in[7];

  // Safe buffer plan (proven in R3/R4):
  //   H1 = d_out (dead before layer-3 writes).
  //   H2 = d_ws if it fits 64 MB, else the dead X input buffer.
  const size_t needed = (size_t)NB * DIM * sizeof(float);
  float* H1  = (float*)d_out;
  float* H2  = (ws_size >= needed) ? (float*)d_ws : (float*)d_in[0];
  float* out = (float*)d_out;

  dim3 grid(NB / 64, DIM / 32);
  dim3 block(256);

  moe_layer<true ><<<grid, block, 0, stream>>>(X,  phi, W1, b1, H1);
  moe_layer<true ><<<grid, block, 0, stream>>>(H1, phi, W2, b2, H2);
  moe_layer<false><<<grid, block, 0, stream>>>(H2, phi, W3, b3, out);
}

// Round 6
// 617.189 us; speedup vs baseline: 2.0977x; 2.0496x over previous
//
#include <hip/hip_runtime.h>
#include <math.h>

#define NB 65536
#define DIM 256

typedef _Float16 half8  __attribute__((ext_vector_type(8)));   // 4 VGPRs
typedef _Float16 half2v __attribute__((ext_vector_type(2)));
typedef float    f32x4  __attribute__((ext_vector_type(4)));

// One cyclic-MoE layer: Out[b,:] = act( sum_e C[b,e]*(X[b,:] @ W_e + bias_e) )
// X-stationary fp16 MFMA design:
//   block = 256 threads (4 waves), owns 128 rows x all 256 cols.
//   A-fragments (fp16) held in VGPRs for the whole kernel; inner loops over
//   8 n-tiles x 4 experts re-stage W (L2-resident, tiny) into LDS.
//   Runtime-probed MFMA C/D layout (proven in R5 — self-correcting indexing).
// acc_scale: multiplier for MFMA result (undoes input pre-scaling).
// store_scale: multiplier applied just before store (pre-scales fp16 output).
template<bool IN_F16, bool OUT_F16, bool RELU>
__global__ __launch_bounds__(256) void moe_layer(
    const void* __restrict__ Xin_,
    const float* __restrict__ phi,
    const float* __restrict__ W,     // [4,256,256] row-major [e][k][n], fp32
    const float* __restrict__ bias,  // [4,256] fp32
    void* __restrict__ Out_,
    float acc_scale, float store_scale)
{
  // Row stride 264 halves = 528 B = 33*16: every [n][k-chunk] half8 is 16B
  // aligned (ds_read_b128 legal) and read start-banks are uniform (no
  // read conflicts beyond the structural minimum).
  __shared__ _Float16 sB[32][264];   // W_e[:, n-tile] transposed: [n_local][k]
  __shared__ float sC[128][4];       // per-row expert coefficients
  __shared__ float sBias[4][DIM];

  const int tid  = threadIdx.x;
  const int row0 = blockIdx.x * 128;
  const int wave = tid >> 6;
  const int lane = tid & 63;
  const int quad = lane >> 4;
  const int l15  = lane & 15;

  // --- LAYOUT PROBE (proven in R5): measure true (lane,reg)->(row,col) ---
  int rowId[4], colId[4];
  {
    half8 vone, vlan;
    #pragma unroll
    for (int j = 0; j < 8; ++j) {
      vone[j] = (_Float16)1.0f;
      vlan[j] = (_Float16)(float)l15;
    }
    const f32x4 z4 = {0.f, 0.f, 0.f, 0.f};
    const f32x4 pm = __builtin_amdgcn_mfma_f32_16x16x32_f16(vlan, vone, z4, 0, 0, 0);
    const f32x4 pn = __builtin_amdgcn_mfma_f32_16x16x32_f16(vone, vlan, z4, 0, 0, 0);
    #pragma unroll
    for (int r = 0; r < 4; ++r) {
      rowId[r] = ((int)(pm[r] * 0.03125f + 0.5f)) & 15;
      colId[r] = ((int)(pn[r] * 0.03125f + 0.5f)) & 15;
    }
  }

  // --- per-row mixing coefficients (reference _phase_mix) ---
  if (tid < 128) {
    const float w  = phi[row0 + tid] * (float)(2.0 / M_PI);  // [0,4]
    const int   wi = (int)w;                                 // trunc toward zero
    const float w2 = w * w, w3 = w2 * w;
    const float cf[4] = {
      -0.5f * w + w2 - 0.5f * w3,
      -2.5f * w2 + 1.5f * w3,
       0.5f * w + 2.0f * w2 - 1.5f * w3,
      -0.5f * w2 + 0.5f * w3 };
    #pragma unroll
    for (int e = 0; e < 4; ++e) sC[tid][e] = cf[(e + 1 - wi) & 3];  // (wi+i-1)%4==e
  }
  #pragma unroll
  for (int e = 0; e < 4; ++e) sBias[e][tid] = bias[e * DIM + tid];

  // --- A fragments (fp16), 2 m-tiles x 8 k-chunks, in VGPRs for whole kernel ---
  half8 afr[2][8];
  #pragma unroll
  for (int m = 0; m < 2; ++m) {
    const size_t row = (size_t)(row0 + m * 64 + wave * 16 + l15);
    if (IN_F16) {
      const _Float16* xr = (const _Float16*)Xin_ + row * DIM;
      #pragma unroll
      for (int kb = 0; kb < 8; ++kb)
        afr[m][kb] = *(const half8*)(xr + kb * 32 + quad * 8);
    } else {
      const float* xr = (const float*)Xin_ + row * DIM;
      #pragma unroll
      for (int kb = 0; kb < 8; ++kb) {
        const float4 a = *(const float4*)(xr + kb * 32 + quad * 8);
        const float4 b = *(const float4*)(xr + kb * 32 + quad * 8 + 4);
        half8 h;
        h[0] = (_Float16)a.x; h[1] = (_Float16)a.y;
        h[2] = (_Float16)a.z; h[3] = (_Float16)a.w;
        h[4] = (_Float16)b.x; h[5] = (_Float16)b.y;
        h[6] = (_Float16)b.z; h[7] = (_Float16)b.w;
        afr[m][kb] = h;
      }
    }
  }

  // --- n-tile loop: 8 tiles of 32 cols; per tile, 4 experts ---
  for (int nt = 0; nt < 8; ++nt) {
    float fin[2][2][4];
    #pragma unroll
    for (int m = 0; m < 2; ++m)
      #pragma unroll
      for (int t = 0; t < 2; ++t)
        #pragma unroll
        for (int r = 0; r < 4; ++r) fin[m][t][r] = 0.f;

    for (int e = 0; e < 4; ++e) {
      __syncthreads();  // sB safe to overwrite (also covers sC/sBias at start)

      // --- stage W_e[:, nt*32 .. +32) into LDS as fp16, [n][k] layout ---
      // Each thread: 2 consecutive k-rows x 4 n, written as packed half2
      // (dword-granular writes; <=4-way bank aliasing).
      const float* We = W + (size_t)e * DIM * DIM + nt * 32;
      #pragma unroll
      for (int it = 0; it < 4; ++it) {
        const int p  = it * 256 + tid;   // 1024 (k-pair, n4) units
        const int k2 = p >> 3;           // 0..127
        const int c  = (p & 7) * 4;      // n_local start
        const int k  = k2 * 2;
        const float4 v0 = *(const float4*)(We + (size_t)k * DIM + c);
        const float4 v1 = *(const float4*)(We + (size_t)(k + 1) * DIM + c);
        const float s0[4] = {v0.x, v0.y, v0.z, v0.w};
        const float s1[4] = {v1.x, v1.y, v1.z, v1.w};
        #pragma unroll
        for (int j = 0; j < 4; ++j) {
          half2v h;
          h[0] = (_Float16)s0[j];
          h[1] = (_Float16)s1[j];
          *(half2v*)&sB[c + j][k] = h;
        }
      }
      __syncthreads();

      // --- MFMA over K=256; B-fragment reused across 2 m-tiles ---
      f32x4 acc[2][2];
      #pragma unroll
      for (int m = 0; m < 2; ++m)
        #pragma unroll
        for (int t = 0; t < 2; ++t) acc[m][t] = (f32x4){0.f, 0.f, 0.f, 0.f};

      #pragma unroll
      for (int kb = 0; kb < 8; ++kb) {
        #pragma unroll
        for (int t = 0; t < 2; ++t) {
          const half8 b = *(const half8*)&sB[t * 16 + l15][kb * 32 + quad * 8];
          acc[0][t] = __builtin_amdgcn_mfma_f32_16x16x32_f16(afr[0][kb], b, acc[0][t], 0, 0, 0);
          acc[1][t] = __builtin_amdgcn_mfma_f32_16x16x32_f16(afr[1][kb], b, acc[1][t], 0, 0, 0);
        }
      }

      // --- combine: fin += C[row,e] * acc_e (probe-driven row) ---
      #pragma unroll
      for (int m = 0; m < 2; ++m)
        #pragma unroll
        for (int r = 0; r < 4; ++r) {
          const float ce = sC[m * 64 + wave * 16 + rowId[r]][e];
          fin[m][0][r] += ce * acc[m][0][r];
          fin[m][1][r] += ce * acc[m][1][r];
        }
    }

    // --- epilogue for this n-tile ---
    #pragma unroll
    for (int m = 0; m < 2; ++m)
      #pragma unroll
      for (int r = 0; r < 4; ++r) {
        const int row_l = m * 64 + wave * 16 + rowId[r];
        #pragma unroll
        for (int t = 0; t < 2; ++t) {
          const int n_l = nt * 32 + t * 16 + colId[r];
          float v = acc_scale * fin[m][t][r];
          #pragma unroll
          for (int e = 0; e < 4; ++e) v += sC[row_l][e] * sBias[e][n_l];
          if (RELU) v = fmaxf(v, 0.f);
          v *= store_scale;
          const size_t idx = (size_t)(row0 + row_l) * DIM + n_l;
          if (OUT_F16) ((_Float16*)Out_)[idx] = (_Float16)v;
          else         ((float*)Out_)[idx] = v;
        }
      }
  }
}

extern "C" void kernel_launch(void* const* d_in, const int* in_sizes, int n_in,
                              void* d_out, int out_size, void* d_ws, size_t ws_size,
                              hipStream_t stream) {
  const float* X   = (const float*)d_in[0];
  const float* phi = (const float*)d_in[1];
  const float* W1  = (const float*)d_in[2];
  const float* b1  = (const float*)d_in[3];
  const float* W2  = (const float*)d_in[4];
  const float* b2  = (const float*)d_in[5];
  const float* W3  = (const float*)d_in[6];
  const float* b3  = (const float*)d_in[7];

  // Buffer plan (safe — proven pattern from R3/R5):
  //   H1 fp16 (32 MB) -> lower half of d_out (d_out only written by layer 3).
  //   H2 fp16 (32 MB) -> d_ws if it fits, else the dead X input buffer
  //     (X fully consumed by layer 1; harness restores d_in every launch).
  //   H2 stored pre-scaled by 1/8 (fp16 range safety); layer 3 undoes (x8).
  const size_t h2_bytes = (size_t)NB * DIM * sizeof(_Float16);
  _Float16* H1 = (_Float16*)d_out;
  _Float16* H2 = (ws_size >= h2_bytes) ? (_Float16*)d_ws : (_Float16*)d_in[0];
  float* out = (float*)d_out;

  dim3 grid(NB / 128);
  dim3 block(256);

  moe_layer<false, true,  true ><<<grid, block, 0, stream>>>(X,  phi, W1, b1, H1,  1.0f, 1.0f);
  moe_layer<true,  true,  true ><<<grid, block, 0, stream>>>(H1, phi, W2, b2, H2,  1.0f, 0.125f);
  moe_layer<true,  false, false><<<grid, block, 0, stream>>>(H2, phi, W3, b3, out, 8.0f, 1.0f);
}